// Round 9
// baseline (677.689 us; speedup 1.0000x reference)
//
#include <hip/hip_runtime.h>
#include <hip/hip_bf16.h>
#include <stdint.h>

#define B_SZ 4096
#define D_SZ 1280
#define L_SZ 16384
#define K_TOP 64
#define C_CAP 192
#define BAND 0.07f
#define CL_CAP 512
#define T_COLLECT 2.2f

typedef __attribute__((ext_vector_type(8))) short s16x8;
typedef __attribute__((ext_vector_type(4))) float f32x4;

#define GLOAD_LDS16(gp, lp)                                                          \
  __builtin_amdgcn_global_load_lds((const __attribute__((address_space(1))) void*)(gp), \
                                   (__attribute__((address_space(3))) void*)(lp), 16, 0, 0)

static __device__ __forceinline__ unsigned short f2bf(float f) {
  __hip_bfloat16 h = __float2bfloat16(f);
  return *reinterpret_cast<unsigned short*>(&h);
}
static __device__ __forceinline__ float bf2f(unsigned short u) {
  return __uint_as_float((unsigned)u << 16);
}
// order-preserving f32 <-> u32 key
static __device__ __forceinline__ unsigned mkkey(float f) {
  const unsigned u = __float_as_uint(f);
  return (u & 0x80000000u) ? ~u : (u | 0x80000000u);
}
static __device__ __forceinline__ float unkey(unsigned k) {
  const unsigned u = (k & 0x80000000u) ? (k & 0x7fffffffu) : ~k;
  return __uint_as_float(u);
}

// -------- fused prep: W_encT(f32+bf16) | A,xs = x-pb | Wd bf16 | zero bk_cnt | zero cl_cnt
__global__ __launch_bounds__(256) void sae_prep(const float* __restrict__ x,
                                                const float* __restrict__ pb,
                                                const float* __restrict__ We,
                                                const float* __restrict__ Wd,
                                                unsigned short* __restrict__ A,
                                                float* __restrict__ xs,
                                                float* __restrict__ WT,
                                                unsigned short* __restrict__ WbT,
                                                unsigned short* __restrict__ Wdb,
                                                int* __restrict__ bk_cnt,
                                                int* __restrict__ cl_cnt) {
  const int b = blockIdx.x, t = threadIdx.x;
  if (b < 5120) {  // W_enc transpose tiles: 256 l-tiles x 20 d-tiles
    __shared__ float tile[64][65];
    const int l0 = (b & 255) * 64, d0 = (b >> 8) * 64;
    const int c = t & 63, rg = t >> 6;
#pragma unroll
    for (int i = 0; i < 16; ++i) {
      const int row = i * 4 + rg;
      tile[row][c] = We[(size_t)(d0 + row) * L_SZ + l0 + c];
    }
    __syncthreads();
#pragma unroll
    for (int i = 0; i < 16; ++i) {
      const int row = i * 4 + rg;
      const float v = tile[c][row];
      const size_t o = (size_t)(l0 + row) * D_SZ + d0 + c;
      WT[o] = v;
      WbT[o] = f2bf(v);
    }
  } else if (b < 5120 + 4096) {  // x - pb
    const int r = b - 5120;
    const float* xr = x + (size_t)r * D_SZ;
    unsigned short* ar = A + (size_t)r * D_SZ;
    float* sr = xs + (size_t)r * D_SZ;
    for (int d = t; d < D_SZ; d += 256) {
      const float v = xr[d] - pb[d];
      ar[d] = f2bf(v);
      sr[d] = v;
    }
  } else if (b < 5120 + 4096 + 2048) {  // W_dec -> bf16
    const int n4 = L_SZ * D_SZ / 4;
    for (int i = (b - 9216) * 256 + t; i < n4; i += 2048 * 256) {
      const float4 v = ((const float4*)Wd)[i];
      ushort4 o;
      o.x = f2bf(v.x); o.y = f2bf(v.y); o.z = f2bf(v.z); o.w = f2bf(v.w);
      ((ushort4*)Wdb)[i] = o;
    }
  } else if (b < 11328) {  // 64 blocks: zero bucket counts (fallback chain)
    bk_cnt[(b - 11264) * 256 + t] = 0;
  } else {  // 16 blocks: zero per-row candidate counters
    cl_cnt[(b - 11328) * 256 + t] = 0;
  }
}

// ------------------------- encode GEMM, 256x256 8-phase + epilogue candidate collection
#define SWZ(lin) ((lin) ^ ((((lin) >> 9) & 7) << 4))
#define A_LDS 0
#define B_LDS 65536
#define KBYTES (D_SZ * 2)

#define PH_MID()                                          \
  __builtin_amdgcn_s_barrier();                           \
  asm volatile("s_waitcnt lgkmcnt(0)" ::: "memory");      \
  __builtin_amdgcn_sched_barrier(0);                      \
  __builtin_amdgcn_s_setprio(1)

#define PH_END()                                          \
  __builtin_amdgcn_s_setprio(0);                          \
  __builtin_amdgcn_s_barrier();                           \
  __builtin_amdgcn_sched_barrier(0)

__global__ __launch_bounds__(512, 2) void sae_gemm(const unsigned short* __restrict__ A,
                                                   const unsigned short* __restrict__ WT,
                                                   const float* __restrict__ lb,
                                                   float* __restrict__ zpre,
                                                   int* __restrict__ cl_cnt,
                                                   int* __restrict__ cl_idx,
                                                   float* __restrict__ cl_val) {
  __shared__ short lds[65536];  // 128 KiB
  char* ldsc = (char*)lds;
  const int t = threadIdx.x, lane = t & 63, w = t >> 6;
  const int wr = w >> 2, wc = w & 3, w2 = w * 2;

  const int bid = blockIdx.x;
  const int xcd = bid & 7, i2 = bid >> 3;
  const int b2 = i2 >> 4, inner = i2 & 15;
  const int mt = (b2 & 3) * 4 + (inner & 3);
  const int nt = xcd * 8 + (b2 >> 2) * 4 + (inner >> 2);
  const int m0 = mt * 256, n0 = nt * 256;

  f32x4 acc[8][4] = {};

  auto STAGE = [&](const unsigned short* op, int rowbase, int ldsop, int buf, int half, int tile) {
#pragma unroll
    for (int s = 0; s < 2; ++s) {
      const int o = (w2 + s) * 1024 + lane * 16;
      const int r = o >> 7;
      const int cb = (o & 127) ^ (((o >> 9) & 7) << 4);
      const char* g = (const char*)op + (size_t)(rowbase + half * 128 + r) * KBYTES +
                      tile * 128 + cb;
      char* l = ldsc + ldsop + buf * 32768 + half * 16384 + (w2 + s) * 1024;
      GLOAD_LDS16(g, l);
    }
  };
  auto LDA = [&](s16x8* af, int buf, int q) {
#pragma unroll
    for (int i = 0; i < 2; ++i)
#pragma unroll
      for (int kk = 0; kk < 2; ++kk) {
        const int r = (q * 2 + i) * 16 + (lane & 15);
        int lin = r * 128 + kk * 64 + ((lane >> 4) * 16);
        lin = SWZ(lin);
        af[i * 2 + kk] = *(const s16x8*)(ldsc + A_LDS + buf * 32768 + wr * 16384 + lin);
      }
  };
  auto LDB = [&](s16x8* bg, int buf) {
#pragma unroll
    for (int j = 0; j < 4; ++j)
#pragma unroll
      for (int kk = 0; kk < 2; ++kk) {
        const int nloc = wc * 64 + j * 16 + (lane & 15);
        const int half = nloc >> 7, r = nloc & 127;
        int lin = r * 128 + kk * 64 + ((lane >> 4) * 16);
        lin = SWZ(lin);
        bg[j * 2 + kk] = *(const s16x8*)(ldsc + B_LDS + buf * 32768 + half * 16384 + lin);
      }
  };
  auto MM = [&](s16x8* af, s16x8* bg, int q) {
#pragma unroll
    for (int i = 0; i < 2; ++i)
#pragma unroll
      for (int j = 0; j < 4; ++j)
#pragma unroll
        for (int kk = 0; kk < 2; ++kk)
          acc[q * 2 + i][j] =
              __builtin_amdgcn_mfma_f32_16x16x32_bf16(af[i * 2 + kk], bg[j * 2 + kk],
                                                      acc[q * 2 + i][j], 0, 0, 0);
  };

  STAGE(WT, n0, B_LDS, 0, 0, 0); STAGE(WT, n0, B_LDS, 0, 1, 0);
  STAGE(A, m0, A_LDS, 0, 0, 0);  STAGE(A, m0, A_LDS, 0, 1, 0);
  STAGE(WT, n0, B_LDS, 1, 0, 1); STAGE(WT, n0, B_LDS, 1, 1, 1);
  asm volatile("s_waitcnt vmcnt(4)" ::: "memory");
  __builtin_amdgcn_s_barrier();
  __builtin_amdgcn_sched_barrier(0);

  const int NI = D_SZ / 128;
  for (int i = 0; i < NI; ++i) {
    const bool last = (i == NI - 1);
    s16x8 af[4], bg[8];
    LDB(bg, 0); LDA(af, 0, 0);
    STAGE(A, m0, A_LDS, 1, 0, 2 * i + 1); STAGE(A, m0, A_LDS, 1, 1, 2 * i + 1);
    PH_MID(); MM(af, bg, 0); PH_END();
    LDA(af, 0, 1);
    if (!last) STAGE(WT, n0, B_LDS, 0, 0, 2 * i + 2);
    PH_MID(); MM(af, bg, 1); PH_END();
    LDA(af, 0, 2);
    if (!last) STAGE(WT, n0, B_LDS, 0, 1, 2 * i + 2);
    PH_MID(); MM(af, bg, 2); PH_END();
    LDA(af, 0, 3);
    PH_MID(); MM(af, bg, 3);
    __builtin_amdgcn_s_setprio(0);
    if (last) { asm volatile("s_waitcnt vmcnt(0)" ::: "memory"); }
    else      { asm volatile("s_waitcnt vmcnt(4)" ::: "memory"); }
    __builtin_amdgcn_s_barrier();
    __builtin_amdgcn_sched_barrier(0);
    LDB(bg, 1); LDA(af, 1, 0);
    if (!last) STAGE(A, m0, A_LDS, 0, 0, 2 * i + 2);
    PH_MID(); MM(af, bg, 0); PH_END();
    LDA(af, 1, 1);
    if (!last) STAGE(A, m0, A_LDS, 0, 1, 2 * i + 2);
    PH_MID(); MM(af, bg, 1); PH_END();
    LDA(af, 1, 2);
    if (!last) STAGE(WT, n0, B_LDS, 1, 0, 2 * i + 3);
    PH_MID(); MM(af, bg, 2); PH_END();
    LDA(af, 1, 3);
    if (!last) STAGE(WT, n0, B_LDS, 1, 1, 2 * i + 3);
    PH_MID(); MM(af, bg, 3);
    __builtin_amdgcn_s_setprio(0);
    asm volatile("s_waitcnt vmcnt(4)" ::: "memory");
    __builtin_amdgcn_s_barrier();
    __builtin_amdgcn_sched_barrier(0);
  }

  // epilogue: store zpre + collect candidates >= T_COLLECT into per-row lists
  const int cl = lane & 15, rg = lane >> 4;
#pragma unroll
  for (int j = 0; j < 4; ++j) {
    const int cc = n0 + wc * 64 + j * 16 + cl;
    const float bias = lb[cc];
#pragma unroll
    for (int i = 0; i < 8; ++i) {
      const int row0 = m0 + wr * 128 + i * 16 + rg * 4;
      const size_t base = (size_t)row0 * L_SZ + cc;
#pragma unroll
      for (int tt = 0; tt < 4; ++tt) {
        const float v = acc[i][j][tt] + bias;
        zpre[base + (size_t)tt * L_SZ] = v;
        if (v >= T_COLLECT) {
          const int p = atomicAdd(&cl_cnt[row0 + tt], 1);
          if (p < CL_CAP) {
            cl_idx[(size_t)(row0 + tt) * CL_CAP + p] = cc;
            cl_val[(size_t)(row0 + tt) * CL_CAP + p] = v;
          }
        }
      }
    }
  }
}

// ---------------------------------------------------------------- radix helper (256-thr blocks)
__device__ void radix_pick(unsigned* hist, unsigned* suf, int* sh_b, unsigned* sh_above,
                           int target, int t) {
  if (t == 0) *sh_b = -1;
  unsigned p = hist[4 * t] + hist[4 * t + 1] + hist[4 * t + 2] + hist[4 * t + 3];
  suf[t] = p;
  for (int off = 1; off < 256; off <<= 1) {
    __syncthreads();
    unsigned v = (t + off < 256) ? suf[t + off] : 0u;
    __syncthreads();
    suf[t] += v;
  }
  __syncthreads();
  const unsigned shi = (t + 1 < 256) ? suf[t + 1] : 0u;
  unsigned S = shi;
  int best = -1;
#pragma unroll
  for (int i = 3; i >= 0; --i) {
    S += hist[4 * t + i];
    if (S >= (unsigned)target) { best = 4 * t + i; break; }
  }
  if (best >= 0) atomicMax(sh_b, best);
  __syncthreads();
  const int b = *sh_b;
  if ((b >> 2) == t) {
    unsigned above = shi;
    for (int i = 3; i > (b & 3); --i) above += hist[4 * t + i];
    *sh_above = above;
  }
  __syncthreads();
}

// ------------- radix helper for 512-thr blocks over 4-copy interleaved hist4[bin*4+copy]
__device__ void radix_pick4(unsigned* hist4, unsigned* suf, int* sh_b, unsigned* sh_above,
                            int target, int t) {
  if (t == 0) *sh_b = -1;
  if (t < 256) {
    unsigned p = 0;
#pragma unroll
    for (int i = 0; i < 4; ++i)
#pragma unroll
      for (int c = 0; c < 4; ++c) p += hist4[(4 * t + i) * 4 + c];
    suf[t] = p;
  }
  for (int off = 1; off < 256; off <<= 1) {
    __syncthreads();
    unsigned v = (t < 256 && t + off < 256) ? suf[t + off] : 0u;
    __syncthreads();
    if (t < 256) suf[t] += v;
  }
  __syncthreads();
  if (t < 256) {
    const unsigned shi = (t + 1 < 256) ? suf[t + 1] : 0u;
    unsigned S = shi;
    int best = -1;
    for (int i = 3; i >= 0; --i) {
      unsigned cnt = 0;
#pragma unroll
      for (int c = 0; c < 4; ++c) cnt += hist4[(4 * t + i) * 4 + c];
      S += cnt;
      if (S >= (unsigned)target) { best = 4 * t + i; break; }
    }
    if (best >= 0) atomicMax(sh_b, best);
  }
  __syncthreads();
  const int b = *sh_b;
  if (t < 256 && (b >> 2) == t) {
    unsigned above = (t + 1 < 256) ? suf[t + 1] : 0u;
    for (int i = 3; i > (b & 3); --i) {
      unsigned cnt = 0;
#pragma unroll
      for (int c = 0; c < 4; ++c) cnt += hist4[(4 * t + i) * 4 + c];
      above += cnt;
    }
    *sh_above = above;
  }
  __syncthreads();
}

// ======== MEGA v3: epilogue-collected list + list radix + band f64 + decode + z-write ========
// Fast path: radix over the per-row list collected by the GEMM (validated: 64<=n<=CL_CAP and
// T<=lo_f). Slow path (exact, never expected): full 3-pass histogram over the zpre row.
__global__ __launch_bounds__(512) void sae_mega(const float* __restrict__ zpre,
                                                const float* __restrict__ xs,
                                                const float* __restrict__ WT,
                                                const float* __restrict__ lb,
                                                const unsigned short* __restrict__ Wdb,
                                                const float* __restrict__ pb,
                                                const int* __restrict__ cl_cnt,
                                                const int* __restrict__ cl_idx,
                                                const float* __restrict__ cl_val,
                                                float* __restrict__ z,
                                                float* __restrict__ xhat) {
  __shared__ unsigned hist4[4096];      // 16 KB
  __shared__ unsigned suf[256];
  __shared__ int l_idx[CL_CAP];         // 2 KB
  __shared__ unsigned l_key[CL_CAP];    // 2 KB
  __shared__ int sh_b0, sh_b1, sh_nhi, sh_nband;
  __shared__ unsigned sh_above;
  __shared__ int bl[C_CAP];
  __shared__ float bfv[C_CAP];
  __shared__ double be[C_CAP];
  __shared__ int ids[K_TOP];
  __shared__ float vs[K_TOP];

  const int r = blockIdx.x, t = threadIdx.x, lane = t & 63, w = t >> 6;
  const float4* zr4 = (const float4*)(zpre + (size_t)r * L_SZ);

  // cache xs row in regs (used by band f64 dots)
  float4 xc[5];
  {
    const float4* xr4 = (const float4*)(xs + (size_t)r * D_SZ);
#pragma unroll
    for (int i = 0; i < 5; ++i) xc[i] = xr4[lane + 64 * i];
  }

  if (t == 0) { sh_nhi = 0; sh_nband = 0; }
  const int n_raw = cl_cnt[r];
  bool fast = (n_raw >= K_TOP && n_raw <= CL_CAP);
  float lo_f = 0.f, hi_f = 0.f;

  if (fast) {
    for (int i = t; i < n_raw; i += 512) {
      l_idx[i] = cl_idx[(size_t)r * CL_CAP + i];
      l_key[i] = mkkey(cl_val[(size_t)r * CL_CAP + i]);
    }
    for (int i = t; i < 4096; i += 512) hist4[i] = 0;
    __syncthreads();
    for (int i = t; i < n_raw; i += 512)
      atomicAdd(&hist4[(l_key[i] >> 22) * 4 + (lane & 3)], 1u);
    __syncthreads();
    radix_pick4(hist4, suf, &sh_b0, &sh_above, K_TOP, t);
    const int b0 = sh_b0;
    const int tgt2 = K_TOP - (int)sh_above;
    for (int i = t; i < 4096; i += 512) hist4[i] = 0;
    __syncthreads();
    for (int i = t; i < n_raw; i += 512) {
      const unsigned k = l_key[i];
      if ((int)(k >> 22) == b0) atomicAdd(&hist4[((k >> 12) & 1023u) * 4 + (lane & 3)], 1u);
    }
    __syncthreads();
    radix_pick4(hist4, suf, &sh_b1, &sh_above, tgt2, t);
    const unsigned v64lb_key = (((unsigned)b0 << 10) | (unsigned)sh_b1) << 12;
    lo_f = unkey(v64lb_key) - BAND;
    hi_f = unkey(v64lb_key + 4095u) + BAND;
    if (T_COLLECT > lo_f) fast = false;  // list may not cover the band: fall back
  }
  __syncthreads();
  if (!fast) {
    // full-histogram slow path over the zpre row (exact; not expected for this data)
    for (int i = t; i < 4096; i += 512) hist4[i] = 0;
    __syncthreads();
    for (int i = t; i < L_SZ / 4; i += 512) {
      const float4 v = zr4[i];
      const float va[4] = {v.x, v.y, v.z, v.w};
#pragma unroll
      for (int q = 0; q < 4; ++q)
        atomicAdd(&hist4[(mkkey(va[q]) >> 22) * 4 + (lane & 3)], 1u);
    }
    __syncthreads();
    radix_pick4(hist4, suf, &sh_b0, &sh_above, K_TOP, t);
    const int b0 = sh_b0;
    const int tgt2 = K_TOP - (int)sh_above;
    for (int i = t; i < 4096; i += 512) hist4[i] = 0;
    __syncthreads();
    for (int i = t; i < L_SZ / 4; i += 512) {
      const float4 v = zr4[i];
      const float va[4] = {v.x, v.y, v.z, v.w};
#pragma unroll
      for (int q = 0; q < 4; ++q) {
        const unsigned k = mkkey(va[q]);
        if ((int)(k >> 22) == b0) atomicAdd(&hist4[((k >> 12) & 1023u) * 4 + (lane & 3)], 1u);
      }
    }
    __syncthreads();
    radix_pick4(hist4, suf, &sh_b1, &sh_above, tgt2, t);
    const unsigned v64lb_key = (((unsigned)b0 << 10) | (unsigned)sh_b1) << 12;
    lo_f = unkey(v64lb_key) - BAND;
    hi_f = unkey(v64lb_key + 4095u) + BAND;
  }
  __syncthreads();
  // classification: hi (provably exact top-64) vs band (exact f64 recompute decides)
  if (fast) {
    for (int i = t; i < n_raw; i += 512) {
      const float val = unkey(l_key[i]);
      if (val >= lo_f) {
        if (val > hi_f) {
          const int p = atomicAdd(&sh_nhi, 1);
          if (p < K_TOP) { ids[p] = l_idx[i]; vs[p] = fmaxf(val, 0.f); }
        } else {
          const int p = atomicAdd(&sh_nband, 1);
          if (p < C_CAP) { bl[p] = l_idx[i]; bfv[p] = val; }
        }
      }
    }
  } else {
    for (int i = t; i < L_SZ / 4; i += 512) {
      const float4 v = zr4[i];
      const float va[4] = {v.x, v.y, v.z, v.w};
#pragma unroll
      for (int q = 0; q < 4; ++q) {
        const float val = va[q];
        if (val >= lo_f) {
          if (val > hi_f) {
            const int p = atomicAdd(&sh_nhi, 1);
            if (p < K_TOP) { ids[p] = 4 * i + q; vs[p] = fmaxf(val, 0.f); }
          } else {
            const int p = atomicAdd(&sh_nband, 1);
            if (p < C_CAP) { bl[p] = 4 * i + q; bfv[p] = val; }
          }
        }
      }
    }
  }
  __syncthreads();
  const int nh = sh_nhi < K_TOP ? sh_nhi : K_TOP;
  const int nb = sh_nband < C_CAP ? sh_nband : C_CAP;
  // band: exact f64 dot per item, one wave per item round-robin (WT_f32 rows, LLC-hot)
  for (int e = w; e < nb; e += 8) {
    const int l = bl[e];
    const float4* wr4 = (const float4*)(WT + (size_t)l * D_SZ);
    double acc = 0.0;
#pragma unroll
    for (int i = 0; i < 5; ++i) {
      const float4 wv = wr4[lane + 64 * i];
      acc += (double)xc[i].x * (double)wv.x + (double)xc[i].y * (double)wv.y +
             (double)xc[i].z * (double)wv.z + (double)xc[i].w * (double)wv.w;
    }
#pragma unroll
    for (int off = 32; off > 0; off >>= 1) acc += __shfl_down(acc, off);
    if (lane == 0) be[e] = acc + (double)lb[l];
  }
  __syncthreads();
  // exact rank among band fills slots [nh, 64)
  const int need = K_TOP - nh;
  if (t < nb) {
    const double ev = be[t];
    const int l = bl[t];
    int rank = 0;
    for (int j = 0; j < nb; ++j) {
      const double e2 = be[j];
      if (e2 > ev || (e2 == ev && bl[j] < l)) ++rank;
    }
    if (rank < need) {
      ids[nh + rank] = l;
      vs[nh + rank] = fmaxf(bfv[t], 0.f);
    }
  }
  __syncthreads();
  // decode (threads 0..319) || z-row zero (threads 320..511)
  if (t < 320) {
    float4 acc = ((const float4*)pb)[t];
#pragma unroll 8
    for (int k = 0; k < K_TOP; ++k) {
      const ushort4 wv = ((const ushort4*)(Wdb + (size_t)ids[k] * D_SZ))[t];
      const float vk = vs[k];
      acc.x += vk * bf2f(wv.x);
      acc.y += vk * bf2f(wv.y);
      acc.z += vk * bf2f(wv.z);
      acc.w += vk * bf2f(wv.w);
    }
    ((float4*)(xhat + (size_t)r * D_SZ))[t] = acc;
  } else {
    const int tz = t - 320;
    float4* zr = (float4*)(z + (size_t)r * L_SZ);
    for (int i = tz; i < L_SZ / 4; i += 192) zr[i] = make_float4(0.f, 0.f, 0.f, 0.f);
  }
  __syncthreads();
  if (t < K_TOP) z[(size_t)r * L_SZ + ids[t]] = vs[t];
}

// ================= fallback chain (scratch aliased into z region; R6-proven) =================
__global__ __launch_bounds__(256) void sae_topc(const float* __restrict__ zpre,
                                                int* __restrict__ bk_cnt,
                                                int* __restrict__ band_lat,
                                                float* __restrict__ band_fval,
                                                int* __restrict__ n_hi,
                                                int* __restrict__ n_band,
                                                int* __restrict__ t_idx,
                                                float* __restrict__ t_val) {
  __shared__ unsigned hist[1024];
  __shared__ unsigned suf[256];
  __shared__ int sh_b0, sh_b1, sh_nhi, sh_nband;
  __shared__ unsigned sh_above;
  const int r = blockIdx.x, t = threadIdx.x;
  const float4* zr4 = (const float4*)(zpre + (size_t)r * L_SZ);

  for (int i = t; i < 1024; i += 256) hist[i] = 0;
  if (t == 0) { sh_nhi = 0; sh_nband = 0; }
  __syncthreads();
  for (int i = t; i < L_SZ / 4; i += 256) {
    const float4 v = zr4[i];
    atomicAdd(&hist[mkkey(v.x) >> 22], 1u);
    atomicAdd(&hist[mkkey(v.y) >> 22], 1u);
    atomicAdd(&hist[mkkey(v.z) >> 22], 1u);
    atomicAdd(&hist[mkkey(v.w) >> 22], 1u);
  }
  __syncthreads();
  radix_pick(hist, suf, &sh_b0, &sh_above, K_TOP, t);
  const int b0 = sh_b0;
  const int target2 = K_TOP - (int)sh_above;
  __syncthreads();
  for (int i = t; i < 1024; i += 256) hist[i] = 0;
  __syncthreads();
  for (int i = t; i < L_SZ / 4; i += 256) {
    const float4 v = zr4[i];
    const float va[4] = {v.x, v.y, v.z, v.w};
#pragma unroll
    for (int q = 0; q < 4; ++q) {
      const unsigned k = mkkey(va[q]);
      if ((int)(k >> 22) == b0) atomicAdd(&hist[(k >> 12) & 1023u], 1u);
    }
  }
  __syncthreads();
  radix_pick(hist, suf, &sh_b1, &sh_above, target2, t);
  const unsigned v64lb_key = (((unsigned)b0 << 10) | (unsigned)sh_b1) << 12;
  const float lo_f = unkey(v64lb_key) - BAND;
  const float hi_f = unkey(v64lb_key + 4095u) + BAND;
  __syncthreads();
  for (int i = t; i < L_SZ / 4; i += 256) {
    const float4 v = zr4[i];
    const float va[4] = {v.x, v.y, v.z, v.w};
#pragma unroll
    for (int q = 0; q < 4; ++q) {
      const float val = va[q];
      if (val >= lo_f) {
        const int l = 4 * i + q;
        if (val > hi_f) {
          const int p = atomicAdd(&sh_nhi, 1);
          if (p < K_TOP) {
            t_idx[(size_t)r * K_TOP + p] = l;
            t_val[(size_t)r * K_TOP + p] = fmaxf(val, 0.f);
          }
        } else {
          const int p = atomicAdd(&sh_nband, 1);
          if (p < C_CAP) {
            band_lat[(r << 8) + p] = l;
            band_fval[(r << 8) + p] = val;
            atomicAdd(&bk_cnt[l], 1);
          }
        }
      }
    }
  }
  __syncthreads();
  if (t == 0) {
    n_hi[r] = sh_nhi < K_TOP ? sh_nhi : K_TOP;
    n_band[r] = sh_nband < C_CAP ? sh_nband : C_CAP;
  }
}

__global__ __launch_bounds__(256) void sae_scan(const int* __restrict__ counts,
                                                int* __restrict__ offsets,
                                                int* __restrict__ cursor) {
  __shared__ int part[256];
  const int t = threadIdx.x;
  int s = 0;
  for (int i = 0; i < 64; ++i) s += counts[t * 64 + i];
  part[t] = s;
  __syncthreads();
  int excl = 0;
  for (int j = 0; j < t; ++j) excl += part[j];
  int run = excl;
  for (int i = 0; i < 64; ++i) {
    const int idx = t * 64 + i;
    offsets[idx] = run;
    cursor[idx] = run;
    run += counts[idx];
  }
}

__global__ __launch_bounds__(192) void sae_bucket_fill(const int* __restrict__ band_lat,
                                                       const int* __restrict__ n_band,
                                                       int* __restrict__ cursor,
                                                       int* __restrict__ entries) {
  const int r = blockIdx.x, t = threadIdx.x;
  if (t < n_band[r]) {
    const int l = band_lat[(r << 8) + t];
    const int pos = atomicAdd(&cursor[l], 1);
    entries[pos] = (r << 8) | t;
  }
}

__global__ __launch_bounds__(256) void sae_refine_lm(const float* __restrict__ xs,
                                                     const float* __restrict__ WT,
                                                     const float* __restrict__ lb,
                                                     const int* __restrict__ counts,
                                                     const int* __restrict__ offsets,
                                                     const int* __restrict__ entries,
                                                     double* __restrict__ band_eval) {
  __shared__ float4 wl[D_SZ / 4];
  const int l = blockIdx.x;
  const int t = threadIdx.x, lane = t & 63, w = t >> 6;
  const int n = counts[l];
  if (n == 0) return;
  const float4* wc = (const float4*)(WT + (size_t)l * D_SZ);
  for (int d = t; d < D_SZ / 4; d += 256) wl[d] = wc[d];
  __syncthreads();
  const int base = offsets[l];
  const double bias = (double)lb[l];
  for (int e = w; e < n; e += 4) {
    const int ent = entries[base + e];
    const int rr = ent >> 8;
    const float4* xr = (const float4*)(xs + (size_t)rr * D_SZ);
    double acc = 0.0;
#pragma unroll
    for (int i = 0; i < 5; ++i) {
      const float4 xv = xr[lane + 64 * i];
      const float4 wv = wl[lane + 64 * i];
      acc += (double)xv.x * (double)wv.x + (double)xv.y * (double)wv.y +
             (double)xv.z * (double)wv.z + (double)xv.w * (double)wv.w;
    }
#pragma unroll
    for (int off = 32; off > 0; off >>= 1) acc += __shfl_down(acc, off);
    if (lane == 0) band_eval[ent] = acc + bias;
  }
}

__global__ __launch_bounds__(320) void sae_finish_nz(const int* __restrict__ n_hi,
                                                     const int* __restrict__ n_band,
                                                     const int* __restrict__ band_lat,
                                                     const float* __restrict__ band_fval,
                                                     const double* __restrict__ band_eval,
                                                     int* __restrict__ t_idx,
                                                     float* __restrict__ t_val,
                                                     const unsigned short* __restrict__ Wdb,
                                                     const float* __restrict__ pb,
                                                     float* __restrict__ xhat) {
  __shared__ int bl[C_CAP];
  __shared__ float bf[C_CAP];
  __shared__ double be[C_CAP];
  __shared__ int ids[K_TOP];
  __shared__ float vs[K_TOP];
  const int r = blockIdx.x, t = threadIdx.x;
  const int nh = n_hi[r], nb = n_band[r];
  if (t < nb) {
    bl[t] = band_lat[(r << 8) + t];
    bf[t] = band_fval[(r << 8) + t];
    be[t] = band_eval[(r << 8) + t];
  }
  if (t < nh) {
    ids[t] = t_idx[(size_t)r * K_TOP + t];
    vs[t] = t_val[(size_t)r * K_TOP + t];
  }
  __syncthreads();
  const int need = K_TOP - nh;
  if (t < nb) {
    const double ev = be[t];
    const int l = bl[t];
    int rank = 0;
    for (int j = 0; j < nb; ++j) {
      const double e2 = be[j];
      if (e2 > ev || (e2 == ev && bl[j] < l)) ++rank;
    }
    if (rank < need) {
      const float fv = fmaxf(bf[t], 0.f);
      ids[nh + rank] = l;
      vs[nh + rank] = fv;
      t_idx[(size_t)r * K_TOP + nh + rank] = l;
      t_val[(size_t)r * K_TOP + nh + rank] = fv;
    }
  }
  __syncthreads();
  float4 acc = ((const float4*)pb)[t];
#pragma unroll 8
  for (int k = 0; k < K_TOP; ++k) {
    const ushort4 wv = ((const ushort4*)(Wdb + (size_t)ids[k] * D_SZ))[t];
    const float vk = vs[k];
    acc.x += vk * bf2f(wv.x);
    acc.y += vk * bf2f(wv.y);
    acc.z += vk * bf2f(wv.z);
    acc.w += vk * bf2f(wv.w);
  }
  ((float4*)(xhat + (size_t)r * D_SZ))[t] = acc;
}

__global__ void sae_scatterA(const int* __restrict__ top_idx, const float* __restrict__ top_val,
                             float* __restrict__ z) {
  const int r = blockIdx.x;
  const int t = threadIdx.x;
  const int id = top_idx[(size_t)r * K_TOP + t];
  const float v = top_val[(size_t)r * K_TOP + t];
  z[(size_t)r * L_SZ + id] = v;
}

__global__ __launch_bounds__(256) void sae_scatterB(const int* __restrict__ top_idx,
                                                    const float* __restrict__ top_val,
                                                    float* __restrict__ z) {
  __shared__ int ids[32 * K_TOP];
  __shared__ float vs[32 * K_TOP];
  const int t = threadIdx.x;
  for (int i = t; i < 32 * K_TOP; i += 256) {
    ids[i] = top_idx[(size_t)4064 * K_TOP + i];
    vs[i] = top_val[(size_t)4064 * K_TOP + i];
  }
  __syncthreads();
  float4* zz = (float4*)(z + (size_t)4064 * L_SZ);
  for (int i = t; i < 32 * L_SZ / 4; i += 256) zz[i] = make_float4(0.f, 0.f, 0.f, 0.f);
  __syncthreads();
  for (int i = t; i < 32 * K_TOP; i += 256) {
    const int rr = 4064 + i / K_TOP;
    z[(size_t)rr * L_SZ + ids[i]] = vs[i];
  }
}

extern "C" void kernel_launch(void* const* d_in, const int* in_sizes, int n_in,
                              void* d_out, int out_size, void* d_ws, size_t ws_size,
                              hipStream_t stream) {
  const float* x  = (const float*)d_in[0];
  const float* pb = (const float*)d_in[1];
  const float* We = (const float*)d_in[2];
  const float* lb = (const float*)d_in[3];
  const float* Wd = (const float*)d_in[4];

  float* zpre = (float*)d_out;
  float* z    = zpre + (size_t)B_SZ * L_SZ;
  float* xhat = z + (size_t)B_SZ * L_SZ;

  const bool use_ws = ws_size >= ((size_t)251 << 20);
  char* sb = use_ws ? (char*)d_ws : (char*)z;

  unsigned short* A_bf   = (unsigned short*)(sb);                        // 10 MiB
  unsigned short* WT_bf  = (unsigned short*)(sb + ((size_t)16 << 20));   // 40 MiB
  float*          WT_f32 = (float*)(sb + ((size_t)64 << 20));            // 80 MiB
  float*          xs_f32 = (float*)(sb + ((size_t)144 << 20));           // 20 MiB
  int*            b_lat  = (int*)(sb + ((size_t)164 << 20));             // 4 MiB
  float*          b_fval = (float*)(sb + ((size_t)168 << 20));           // 4 MiB
  double*         b_eval = (double*)(sb + ((size_t)172 << 20));          // 8 MiB
  int*            bk_cnt = (int*)(sb + ((size_t)180 << 20));             // 64 KiB
  int*            bk_off = (int*)(sb + ((size_t)181 << 20));             // 64 KiB
  int*            bk_cur = (int*)(sb + ((size_t)182 << 20));             // 64 KiB
  int*            bk_ent = (int*)(sb + ((size_t)184 << 20));             // 3 MiB
  unsigned short* Wd_bf  = (unsigned short*)(sb + ((size_t)188 << 20));  // 40 MiB
  int*            nhi_g  = (int*)(sb + ((size_t)228 << 20));             // 16 KiB
  int*            nbd_g  = (int*)(sb + ((size_t)229 << 20));             // 16 KiB
  int*            cl_idx = (int*)(sb + ((size_t)234 << 20));             // 8 MiB
  float*          cl_val = (float*)(sb + ((size_t)242 << 20));           // 8 MiB
  int*            cl_cnt = (int*)(sb + ((size_t)250 << 20));             // 16 KiB
  int*   t_idx = use_ws ? (int*)(sb + ((size_t)230 << 20))
                        : (int*)((char*)z + ((size_t)254 << 20));        // 1 MiB
  float* t_val = use_ws ? (float*)(sb + ((size_t)232 << 20))
                        : (float*)((char*)z + ((size_t)255 << 20));      // 1 MiB

  sae_prep<<<11344, 256, 0, stream>>>(x, pb, We, Wd, A_bf, xs_f32, WT_f32, WT_bf, Wd_bf,
                                      bk_cnt, cl_cnt);
  sae_gemm<<<1024, 512, 0, stream>>>(A_bf, WT_bf, lb, zpre, cl_cnt, cl_idx, cl_val);
  if (use_ws) {
    sae_mega<<<B_SZ, 512, 0, stream>>>(zpre, xs_f32, WT_f32, lb, Wd_bf, pb,
                                       cl_cnt, cl_idx, cl_val, z, xhat);
  } else {
    sae_topc<<<B_SZ, 256, 0, stream>>>(zpre, bk_cnt, b_lat, b_fval, nhi_g, nbd_g, t_idx, t_val);
    sae_scan<<<1, 256, 0, stream>>>(bk_cnt, bk_off, bk_cur);
    sae_bucket_fill<<<B_SZ, 192, 0, stream>>>(b_lat, nbd_g, bk_cur, bk_ent);
    sae_refine_lm<<<L_SZ, 256, 0, stream>>>(xs_f32, WT_f32, lb, bk_cnt, bk_off, bk_ent, b_eval);
    sae_finish_nz<<<B_SZ, 320, 0, stream>>>(nhi_g, nbd_g, b_lat, b_fval, b_eval, t_idx, t_val,
                                            Wd_bf, pb, xhat);
    hipMemsetAsync(z, 0, (size_t)4064 * L_SZ * sizeof(float), stream);
    sae_scatterA<<<4064, K_TOP, 0, stream>>>(t_idx, t_val, z);
    sae_scatterB<<<1, 256, 0, stream>>>(t_idx, t_val, z);
  }
}

// Round 10
// 638.039 us; speedup vs baseline: 1.0621x; 1.0621x over previous
//
#include <hip/hip_runtime.h>
#include <hip/hip_bf16.h>
#include <stdint.h>

#define B_SZ 4096
#define D_SZ 1280
#define L_SZ 16384
#define K_TOP 64
#define C_CAP 192
#define BAND 0.07f
#define CL_CAP 512
#define T_COLLECT 2.2f

typedef __attribute__((ext_vector_type(8))) short s16x8;
typedef __attribute__((ext_vector_type(4))) float f32x4;

#define GLOAD_LDS16(gp, lp)                                                          \
  __builtin_amdgcn_global_load_lds((const __attribute__((address_space(1))) void*)(gp), \
                                   (__attribute__((address_space(3))) void*)(lp), 16, 0, 0)

static __device__ __forceinline__ unsigned short f2bf(float f) {
  __hip_bfloat16 h = __float2bfloat16(f);
  return *reinterpret_cast<unsigned short*>(&h);
}
static __device__ __forceinline__ float bf2f(unsigned short u) {
  return __uint_as_float((unsigned)u << 16);
}
// order-preserving f32 <-> u32 key
static __device__ __forceinline__ unsigned mkkey(float f) {
  const unsigned u = __float_as_uint(f);
  return (u & 0x80000000u) ? ~u : (u | 0x80000000u);
}
static __device__ __forceinline__ float unkey(unsigned k) {
  const unsigned u = (k & 0x80000000u) ? (k & 0x7fffffffu) : ~k;
  return __uint_as_float(u);
}

// -------- fused prep: W_encT(f32+bf16) | A,xs = x-pb | Wd bf16 | zero bk_cnt | zero cl_cnt
__global__ __launch_bounds__(256) void sae_prep(const float* __restrict__ x,
                                                const float* __restrict__ pb,
                                                const float* __restrict__ We,
                                                const float* __restrict__ Wd,
                                                unsigned short* __restrict__ A,
                                                float* __restrict__ xs,
                                                float* __restrict__ WT,
                                                unsigned short* __restrict__ WbT,
                                                unsigned short* __restrict__ Wdb,
                                                int* __restrict__ bk_cnt,
                                                int* __restrict__ cl_cnt) {
  const int b = blockIdx.x, t = threadIdx.x;
  if (b < 5120) {  // W_enc transpose tiles: 256 l-tiles x 20 d-tiles
    __shared__ float tile[64][65];
    const int l0 = (b & 255) * 64, d0 = (b >> 8) * 64;
    const int c = t & 63, rg = t >> 6;
#pragma unroll
    for (int i = 0; i < 16; ++i) {
      const int row = i * 4 + rg;
      tile[row][c] = We[(size_t)(d0 + row) * L_SZ + l0 + c];
    }
    __syncthreads();
#pragma unroll
    for (int i = 0; i < 16; ++i) {
      const int row = i * 4 + rg;
      const float v = tile[c][row];
      const size_t o = (size_t)(l0 + row) * D_SZ + d0 + c;
      WT[o] = v;
      WbT[o] = f2bf(v);
    }
  } else if (b < 5120 + 4096) {  // x - pb
    const int r = b - 5120;
    const float* xr = x + (size_t)r * D_SZ;
    unsigned short* ar = A + (size_t)r * D_SZ;
    float* sr = xs + (size_t)r * D_SZ;
    for (int d = t; d < D_SZ; d += 256) {
      const float v = xr[d] - pb[d];
      ar[d] = f2bf(v);
      sr[d] = v;
    }
  } else if (b < 5120 + 4096 + 2048) {  // W_dec -> bf16
    const int n4 = L_SZ * D_SZ / 4;
    for (int i = (b - 9216) * 256 + t; i < n4; i += 2048 * 256) {
      const float4 v = ((const float4*)Wd)[i];
      ushort4 o;
      o.x = f2bf(v.x); o.y = f2bf(v.y); o.z = f2bf(v.z); o.w = f2bf(v.w);
      ((ushort4*)Wdb)[i] = o;
    }
  } else if (b < 11328) {  // 64 blocks: zero bucket counts (fallback chain)
    bk_cnt[(b - 11264) * 256 + t] = 0;
  } else {  // 16 blocks: zero per-row candidate counters
    cl_cnt[(b - 11328) * 256 + t] = 0;
  }
}

// ------------------------- encode GEMM, 256x256 8-phase + epilogue candidate collection
// LDS swizzle (FIXED R10): XOR byte-bits[6:4] with (row&7) = (lin>>7)&7 — guide G4 recipe.
// (R4-R9 used (lin>>9)&7 = row>>2, which collapsed each wave onto 16 of 32 banks: 4.7e7
// conflict cycles/dispatch, MfmaUtil 20%. Both-sides-consistent so correctness held.)
#define SWZ(lin) ((lin) ^ ((((lin) >> 7) & 7) << 4))
#define A_LDS 0
#define B_LDS 65536
#define KBYTES (D_SZ * 2)

#define PH_MID()                                          \
  __builtin_amdgcn_s_barrier();                           \
  asm volatile("s_waitcnt lgkmcnt(0)" ::: "memory");      \
  __builtin_amdgcn_sched_barrier(0);                      \
  __builtin_amdgcn_s_setprio(1)

#define PH_END()                                          \
  __builtin_amdgcn_s_setprio(0);                          \
  __builtin_amdgcn_s_barrier();                           \
  __builtin_amdgcn_sched_barrier(0)

__global__ __launch_bounds__(512, 2) void sae_gemm(const unsigned short* __restrict__ A,
                                                   const unsigned short* __restrict__ WT,
                                                   const float* __restrict__ lb,
                                                   float* __restrict__ zpre,
                                                   int* __restrict__ cl_cnt,
                                                   int* __restrict__ cl_idx,
                                                   float* __restrict__ cl_val) {
  __shared__ short lds[65536];  // 128 KiB
  char* ldsc = (char*)lds;
  const int t = threadIdx.x, lane = t & 63, w = t >> 6;
  const int wr = w >> 2, wc = w & 3, w2 = w * 2;

  const int bid = blockIdx.x;
  const int xcd = bid & 7, i2 = bid >> 3;
  const int b2 = i2 >> 4, inner = i2 & 15;
  const int mt = (b2 & 3) * 4 + (inner & 3);
  const int nt = xcd * 8 + (b2 >> 2) * 4 + (inner >> 2);
  const int m0 = mt * 256, n0 = nt * 256;

  f32x4 acc[8][4] = {};

  auto STAGE = [&](const unsigned short* op, int rowbase, int ldsop, int buf, int half, int tile) {
#pragma unroll
    for (int s = 0; s < 2; ++s) {
      const int o = (w2 + s) * 1024 + lane * 16;
      const int r = o >> 7;
      const int cb = (o & 127) ^ (((o >> 7) & 7) << 4);  // inverse swizzle (FIXED: >>7)
      const char* g = (const char*)op + (size_t)(rowbase + half * 128 + r) * KBYTES +
                      tile * 128 + cb;
      char* l = ldsc + ldsop + buf * 32768 + half * 16384 + (w2 + s) * 1024;
      GLOAD_LDS16(g, l);
    }
  };
  auto LDA = [&](s16x8* af, int buf, int q) {
#pragma unroll
    for (int i = 0; i < 2; ++i)
#pragma unroll
      for (int kk = 0; kk < 2; ++kk) {
        const int r = (q * 2 + i) * 16 + (lane & 15);
        int lin = r * 128 + kk * 64 + ((lane >> 4) * 16);
        lin = SWZ(lin);
        af[i * 2 + kk] = *(const s16x8*)(ldsc + A_LDS + buf * 32768 + wr * 16384 + lin);
      }
  };
  auto LDB = [&](s16x8* bg, int buf) {
#pragma unroll
    for (int j = 0; j < 4; ++j)
#pragma unroll
      for (int kk = 0; kk < 2; ++kk) {
        const int nloc = wc * 64 + j * 16 + (lane & 15);
        const int half = nloc >> 7, r = nloc & 127;
        int lin = r * 128 + kk * 64 + ((lane >> 4) * 16);
        lin = SWZ(lin);
        bg[j * 2 + kk] = *(const s16x8*)(ldsc + B_LDS + buf * 32768 + half * 16384 + lin);
      }
  };
  auto MM = [&](s16x8* af, s16x8* bg, int q) {
#pragma unroll
    for (int i = 0; i < 2; ++i)
#pragma unroll
      for (int j = 0; j < 4; ++j)
#pragma unroll
        for (int kk = 0; kk < 2; ++kk)
          acc[q * 2 + i][j] =
              __builtin_amdgcn_mfma_f32_16x16x32_bf16(af[i * 2 + kk], bg[j * 2 + kk],
                                                      acc[q * 2 + i][j], 0, 0, 0);
  };

  STAGE(WT, n0, B_LDS, 0, 0, 0); STAGE(WT, n0, B_LDS, 0, 1, 0);
  STAGE(A, m0, A_LDS, 0, 0, 0);  STAGE(A, m0, A_LDS, 0, 1, 0);
  STAGE(WT, n0, B_LDS, 1, 0, 1); STAGE(WT, n0, B_LDS, 1, 1, 1);
  asm volatile("s_waitcnt vmcnt(4)" ::: "memory");
  __builtin_amdgcn_s_barrier();
  __builtin_amdgcn_sched_barrier(0);

  const int NI = D_SZ / 128;
  for (int i = 0; i < NI; ++i) {
    const bool last = (i == NI - 1);
    s16x8 af[4], bg[8];
    LDB(bg, 0); LDA(af, 0, 0);
    STAGE(A, m0, A_LDS, 1, 0, 2 * i + 1); STAGE(A, m0, A_LDS, 1, 1, 2 * i + 1);
    PH_MID(); MM(af, bg, 0); PH_END();
    LDA(af, 0, 1);
    if (!last) STAGE(WT, n0, B_LDS, 0, 0, 2 * i + 2);
    PH_MID(); MM(af, bg, 1); PH_END();
    LDA(af, 0, 2);
    if (!last) STAGE(WT, n0, B_LDS, 0, 1, 2 * i + 2);
    PH_MID(); MM(af, bg, 2); PH_END();
    LDA(af, 0, 3);
    PH_MID(); MM(af, bg, 3);
    __builtin_amdgcn_s_setprio(0);
    if (last) { asm volatile("s_waitcnt vmcnt(0)" ::: "memory"); }
    else      { asm volatile("s_waitcnt vmcnt(4)" ::: "memory"); }
    __builtin_amdgcn_s_barrier();
    __builtin_amdgcn_sched_barrier(0);
    LDB(bg, 1); LDA(af, 1, 0);
    if (!last) STAGE(A, m0, A_LDS, 0, 0, 2 * i + 2);
    PH_MID(); MM(af, bg, 0); PH_END();
    LDA(af, 1, 1);
    if (!last) STAGE(A, m0, A_LDS, 0, 1, 2 * i + 2);
    PH_MID(); MM(af, bg, 1); PH_END();
    LDA(af, 1, 2);
    if (!last) STAGE(WT, n0, B_LDS, 1, 0, 2 * i + 3);
    PH_MID(); MM(af, bg, 2); PH_END();
    LDA(af, 1, 3);
    if (!last) STAGE(WT, n0, B_LDS, 1, 1, 2 * i + 3);
    PH_MID(); MM(af, bg, 3);
    __builtin_amdgcn_s_setprio(0);
    asm volatile("s_waitcnt vmcnt(4)" ::: "memory");
    __builtin_amdgcn_s_barrier();
    __builtin_amdgcn_sched_barrier(0);
  }

  // epilogue: store zpre + collect candidates >= T_COLLECT into per-row lists
  const int cl = lane & 15, rg = lane >> 4;
#pragma unroll
  for (int j = 0; j < 4; ++j) {
    const int cc = n0 + wc * 64 + j * 16 + cl;
    const float bias = lb[cc];
#pragma unroll
    for (int i = 0; i < 8; ++i) {
      const int row0 = m0 + wr * 128 + i * 16 + rg * 4;
      const size_t base = (size_t)row0 * L_SZ + cc;
#pragma unroll
      for (int tt = 0; tt < 4; ++tt) {
        const float v = acc[i][j][tt] + bias;
        zpre[base + (size_t)tt * L_SZ] = v;
        if (v >= T_COLLECT) {
          const int p = atomicAdd(&cl_cnt[row0 + tt], 1);
          if (p < CL_CAP) {
            cl_idx[(size_t)(row0 + tt) * CL_CAP + p] = cc;
            cl_val[(size_t)(row0 + tt) * CL_CAP + p] = v;
          }
        }
      }
    }
  }
}

// ---------------------------------------------------------------- radix helper (256-thr blocks)
__device__ void radix_pick(unsigned* hist, unsigned* suf, int* sh_b, unsigned* sh_above,
                           int target, int t) {
  if (t == 0) *sh_b = -1;
  unsigned p = hist[4 * t] + hist[4 * t + 1] + hist[4 * t + 2] + hist[4 * t + 3];
  suf[t] = p;
  for (int off = 1; off < 256; off <<= 1) {
    __syncthreads();
    unsigned v = (t + off < 256) ? suf[t + off] : 0u;
    __syncthreads();
    suf[t] += v;
  }
  __syncthreads();
  const unsigned shi = (t + 1 < 256) ? suf[t + 1] : 0u;
  unsigned S = shi;
  int best = -1;
#pragma unroll
  for (int i = 3; i >= 0; --i) {
    S += hist[4 * t + i];
    if (S >= (unsigned)target) { best = 4 * t + i; break; }
  }
  if (best >= 0) atomicMax(sh_b, best);
  __syncthreads();
  const int b = *sh_b;
  if ((b >> 2) == t) {
    unsigned above = shi;
    for (int i = 3; i > (b & 3); --i) above += hist[4 * t + i];
    *sh_above = above;
  }
  __syncthreads();
}

// ------------- radix helper for 512-thr blocks over 4-copy interleaved hist4[bin*4+copy]
__device__ void radix_pick4(unsigned* hist4, unsigned* suf, int* sh_b, unsigned* sh_above,
                            int target, int t) {
  if (t == 0) *sh_b = -1;
  if (t < 256) {
    unsigned p = 0;
#pragma unroll
    for (int i = 0; i < 4; ++i)
#pragma unroll
      for (int c = 0; c < 4; ++c) p += hist4[(4 * t + i) * 4 + c];
    suf[t] = p;
  }
  for (int off = 1; off < 256; off <<= 1) {
    __syncthreads();
    unsigned v = (t < 256 && t + off < 256) ? suf[t + off] : 0u;
    __syncthreads();
    if (t < 256) suf[t] += v;
  }
  __syncthreads();
  if (t < 256) {
    const unsigned shi = (t + 1 < 256) ? suf[t + 1] : 0u;
    unsigned S = shi;
    int best = -1;
    for (int i = 3; i >= 0; --i) {
      unsigned cnt = 0;
#pragma unroll
      for (int c = 0; c < 4; ++c) cnt += hist4[(4 * t + i) * 4 + c];
      S += cnt;
      if (S >= (unsigned)target) { best = 4 * t + i; break; }
    }
    if (best >= 0) atomicMax(sh_b, best);
  }
  __syncthreads();
  const int b = *sh_b;
  if (t < 256 && (b >> 2) == t) {
    unsigned above = (t + 1 < 256) ? suf[t + 1] : 0u;
    for (int i = 3; i > (b & 3); --i) {
      unsigned cnt = 0;
#pragma unroll
      for (int c = 0; c < 4; ++c) cnt += hist4[(4 * t + i) * 4 + c];
      above += cnt;
    }
    *sh_above = above;
  }
  __syncthreads();
}

// ======== MEGA v3: epilogue-collected list + list radix + band f64 + decode + z-write ========
__global__ __launch_bounds__(512) void sae_mega(const float* __restrict__ zpre,
                                                const float* __restrict__ xs,
                                                const float* __restrict__ WT,
                                                const float* __restrict__ lb,
                                                const unsigned short* __restrict__ Wdb,
                                                const float* __restrict__ pb,
                                                const int* __restrict__ cl_cnt,
                                                const int* __restrict__ cl_idx,
                                                const float* __restrict__ cl_val,
                                                float* __restrict__ z,
                                                float* __restrict__ xhat) {
  __shared__ unsigned hist4[4096];      // 16 KB
  __shared__ unsigned suf[256];
  __shared__ int l_idx[CL_CAP];         // 2 KB
  __shared__ unsigned l_key[CL_CAP];    // 2 KB
  __shared__ int sh_b0, sh_b1, sh_nhi, sh_nband;
  __shared__ unsigned sh_above;
  __shared__ int bl[C_CAP];
  __shared__ float bfv[C_CAP];
  __shared__ double be[C_CAP];
  __shared__ int ids[K_TOP];
  __shared__ float vs[K_TOP];

  const int r = blockIdx.x, t = threadIdx.x, lane = t & 63, w = t >> 6;
  const float4* zr4 = (const float4*)(zpre + (size_t)r * L_SZ);

  // cache xs row in regs (used by band f64 dots)
  float4 xc[5];
  {
    const float4* xr4 = (const float4*)(xs + (size_t)r * D_SZ);
#pragma unroll
    for (int i = 0; i < 5; ++i) xc[i] = xr4[lane + 64 * i];
  }

  if (t == 0) { sh_nhi = 0; sh_nband = 0; }
  const int n_raw = cl_cnt[r];
  bool fast = (n_raw >= K_TOP && n_raw <= CL_CAP);
  float lo_f = 0.f, hi_f = 0.f;

  if (fast) {
    for (int i = t; i < n_raw; i += 512) {
      l_idx[i] = cl_idx[(size_t)r * CL_CAP + i];
      l_key[i] = mkkey(cl_val[(size_t)r * CL_CAP + i]);
    }
    for (int i = t; i < 4096; i += 512) hist4[i] = 0;
    __syncthreads();
    for (int i = t; i < n_raw; i += 512)
      atomicAdd(&hist4[(l_key[i] >> 22) * 4 + (lane & 3)], 1u);
    __syncthreads();
    radix_pick4(hist4, suf, &sh_b0, &sh_above, K_TOP, t);
    const int b0 = sh_b0;
    const int tgt2 = K_TOP - (int)sh_above;
    for (int i = t; i < 4096; i += 512) hist4[i] = 0;
    __syncthreads();
    for (int i = t; i < n_raw; i += 512) {
      const unsigned k = l_key[i];
      if ((int)(k >> 22) == b0) atomicAdd(&hist4[((k >> 12) & 1023u) * 4 + (lane & 3)], 1u);
    }
    __syncthreads();
    radix_pick4(hist4, suf, &sh_b1, &sh_above, tgt2, t);
    const unsigned v64lb_key = (((unsigned)b0 << 10) | (unsigned)sh_b1) << 12;
    lo_f = unkey(v64lb_key) - BAND;
    hi_f = unkey(v64lb_key + 4095u) + BAND;
    if (T_COLLECT > lo_f) fast = false;  // list may not cover the band: fall back
  }
  __syncthreads();
  if (!fast) {
    // full-histogram slow path over the zpre row (exact; not expected for this data)
    for (int i = t; i < 4096; i += 512) hist4[i] = 0;
    __syncthreads();
    for (int i = t; i < L_SZ / 4; i += 512) {
      const float4 v = zr4[i];
      const float va[4] = {v.x, v.y, v.z, v.w};
#pragma unroll
      for (int q = 0; q < 4; ++q)
        atomicAdd(&hist4[(mkkey(va[q]) >> 22) * 4 + (lane & 3)], 1u);
    }
    __syncthreads();
    radix_pick4(hist4, suf, &sh_b0, &sh_above, K_TOP, t);
    const int b0 = sh_b0;
    const int tgt2 = K_TOP - (int)sh_above;
    for (int i = t; i < 4096; i += 512) hist4[i] = 0;
    __syncthreads();
    for (int i = t; i < L_SZ / 4; i += 512) {
      const float4 v = zr4[i];
      const float va[4] = {v.x, v.y, v.z, v.w};
#pragma unroll
      for (int q = 0; q < 4; ++q) {
        const unsigned k = mkkey(va[q]);
        if ((int)(k >> 22) == b0) atomicAdd(&hist4[((k >> 12) & 1023u) * 4 + (lane & 3)], 1u);
      }
    }
    __syncthreads();
    radix_pick4(hist4, suf, &sh_b1, &sh_above, tgt2, t);
    const unsigned v64lb_key = (((unsigned)b0 << 10) | (unsigned)sh_b1) << 12;
    lo_f = unkey(v64lb_key) - BAND;
    hi_f = unkey(v64lb_key + 4095u) + BAND;
  }
  __syncthreads();
  // classification: hi (provably exact top-64) vs band (exact f64 recompute decides)
  if (fast) {
    for (int i = t; i < n_raw; i += 512) {
      const float val = unkey(l_key[i]);
      if (val >= lo_f) {
        if (val > hi_f) {
          const int p = atomicAdd(&sh_nhi, 1);
          if (p < K_TOP) { ids[p] = l_idx[i]; vs[p] = fmaxf(val, 0.f); }
        } else {
          const int p = atomicAdd(&sh_nband, 1);
          if (p < C_CAP) { bl[p] = l_idx[i]; bfv[p] = val; }
        }
      }
    }
  } else {
    for (int i = t; i < L_SZ / 4; i += 512) {
      const float4 v = zr4[i];
      const float va[4] = {v.x, v.y, v.z, v.w};
#pragma unroll
      for (int q = 0; q < 4; ++q) {
        const float val = va[q];
        if (val >= lo_f) {
          if (val > hi_f) {
            const int p = atomicAdd(&sh_nhi, 1);
            if (p < K_TOP) { ids[p] = 4 * i + q; vs[p] = fmaxf(val, 0.f); }
          } else {
            const int p = atomicAdd(&sh_nband, 1);
            if (p < C_CAP) { bl[p] = 4 * i + q; bfv[p] = val; }
          }
        }
      }
    }
  }
  __syncthreads();
  const int nh = sh_nhi < K_TOP ? sh_nhi : K_TOP;
  const int nb = sh_nband < C_CAP ? sh_nband : C_CAP;
  // band: exact f64 dot per item, one wave per item round-robin (WT_f32 rows, LLC-hot)
  for (int e = w; e < nb; e += 8) {
    const int l = bl[e];
    const float4* wr4 = (const float4*)(WT + (size_t)l * D_SZ);
    double acc = 0.0;
#pragma unroll
    for (int i = 0; i < 5; ++i) {
      const float4 wv = wr4[lane + 64 * i];
      acc += (double)xc[i].x * (double)wv.x + (double)xc[i].y * (double)wv.y +
             (double)xc[i].z * (double)wv.z + (double)xc[i].w * (double)wv.w;
    }
#pragma unroll
    for (int off = 32; off > 0; off >>= 1) acc += __shfl_down(acc, off);
    if (lane == 0) be[e] = acc + (double)lb[l];
  }
  __syncthreads();
  // exact rank among band fills slots [nh, 64)
  const int need = K_TOP - nh;
  if (t < nb) {
    const double ev = be[t];
    const int l = bl[t];
    int rank = 0;
    for (int j = 0; j < nb; ++j) {
      const double e2 = be[j];
      if (e2 > ev || (e2 == ev && bl[j] < l)) ++rank;
    }
    if (rank < need) {
      ids[nh + rank] = l;
      vs[nh + rank] = fmaxf(bfv[t], 0.f);
    }
  }
  __syncthreads();
  // decode (threads 0..319) || z-row zero (threads 320..511)
  if (t < 320) {
    float4 acc = ((const float4*)pb)[t];
#pragma unroll 8
    for (int k = 0; k < K_TOP; ++k) {
      const ushort4 wv = ((const ushort4*)(Wdb + (size_t)ids[k] * D_SZ))[t];
      const float vk = vs[k];
      acc.x += vk * bf2f(wv.x);
      acc.y += vk * bf2f(wv.y);
      acc.z += vk * bf2f(wv.z);
      acc.w += vk * bf2f(wv.w);
    }
    ((float4*)(xhat + (size_t)r * D_SZ))[t] = acc;
  } else {
    const int tz = t - 320;
    float4* zr = (float4*)(z + (size_t)r * L_SZ);
    for (int i = tz; i < L_SZ / 4; i += 192) zr[i] = make_float4(0.f, 0.f, 0.f, 0.f);
  }
  __syncthreads();
  if (t < K_TOP) z[(size_t)r * L_SZ + ids[t]] = vs[t];
}

// ================= fallback chain (scratch aliased into z region; R6-proven) =================
__global__ __launch_bounds__(256) void sae_topc(const float* __restrict__ zpre,
                                                int* __restrict__ bk_cnt,
                                                int* __restrict__ band_lat,
                                                float* __restrict__ band_fval,
                                                int* __restrict__ n_hi,
                                                int* __restrict__ n_band,
                                                int* __restrict__ t_idx,
                                                float* __restrict__ t_val) {
  __shared__ unsigned hist[1024];
  __shared__ unsigned suf[256];
  __shared__ int sh_b0, sh_b1, sh_nhi, sh_nband;
  __shared__ unsigned sh_above;
  const int r = blockIdx.x, t = threadIdx.x;
  const float4* zr4 = (const float4*)(zpre + (size_t)r * L_SZ);

  for (int i = t; i < 1024; i += 256) hist[i] = 0;
  if (t == 0) { sh_nhi = 0; sh_nband = 0; }
  __syncthreads();
  for (int i = t; i < L_SZ / 4; i += 256) {
    const float4 v = zr4[i];
    atomicAdd(&hist[mkkey(v.x) >> 22], 1u);
    atomicAdd(&hist[mkkey(v.y) >> 22], 1u);
    atomicAdd(&hist[mkkey(v.z) >> 22], 1u);
    atomicAdd(&hist[mkkey(v.w) >> 22], 1u);
  }
  __syncthreads();
  radix_pick(hist, suf, &sh_b0, &sh_above, K_TOP, t);
  const int b0 = sh_b0;
  const int target2 = K_TOP - (int)sh_above;
  __syncthreads();
  for (int i = t; i < 1024; i += 256) hist[i] = 0;
  __syncthreads();
  for (int i = t; i < L_SZ / 4; i += 256) {
    const float4 v = zr4[i];
    const float va[4] = {v.x, v.y, v.z, v.w};
#pragma unroll
    for (int q = 0; q < 4; ++q) {
      const unsigned k = mkkey(va[q]);
      if ((int)(k >> 22) == b0) atomicAdd(&hist[(k >> 12) & 1023u], 1u);
    }
  }
  __syncthreads();
  radix_pick(hist, suf, &sh_b1, &sh_above, target2, t);
  const unsigned v64lb_key = (((unsigned)b0 << 10) | (unsigned)sh_b1) << 12;
  const float lo_f = unkey(v64lb_key) - BAND;
  const float hi_f = unkey(v64lb_key + 4095u) + BAND;
  __syncthreads();
  for (int i = t; i < L_SZ / 4; i += 256) {
    const float4 v = zr4[i];
    const float va[4] = {v.x, v.y, v.z, v.w};
#pragma unroll
    for (int q = 0; q < 4; ++q) {
      const float val = va[q];
      if (val >= lo_f) {
        const int l = 4 * i + q;
        if (val > hi_f) {
          const int p = atomicAdd(&sh_nhi, 1);
          if (p < K_TOP) {
            t_idx[(size_t)r * K_TOP + p] = l;
            t_val[(size_t)r * K_TOP + p] = fmaxf(val, 0.f);
          }
        } else {
          const int p = atomicAdd(&sh_nband, 1);
          if (p < C_CAP) {
            band_lat[(r << 8) + p] = l;
            band_fval[(r << 8) + p] = val;
            atomicAdd(&bk_cnt[l], 1);
          }
        }
      }
    }
  }
  __syncthreads();
  if (t == 0) {
    n_hi[r] = sh_nhi < K_TOP ? sh_nhi : K_TOP;
    n_band[r] = sh_nband < C_CAP ? sh_nband : C_CAP;
  }
}

__global__ __launch_bounds__(256) void sae_scan(const int* __restrict__ counts,
                                                int* __restrict__ offsets,
                                                int* __restrict__ cursor) {
  __shared__ int part[256];
  const int t = threadIdx.x;
  int s = 0;
  for (int i = 0; i < 64; ++i) s += counts[t * 64 + i];
  part[t] = s;
  __syncthreads();
  int excl = 0;
  for (int j = 0; j < t; ++j) excl += part[j];
  int run = excl;
  for (int i = 0; i < 64; ++i) {
    const int idx = t * 64 + i;
    offsets[idx] = run;
    cursor[idx] = run;
    run += counts[idx];
  }
}

__global__ __launch_bounds__(192) void sae_bucket_fill(const int* __restrict__ band_lat,
                                                       const int* __restrict__ n_band,
                                                       int* __restrict__ cursor,
                                                       int* __restrict__ entries) {
  const int r = blockIdx.x, t = threadIdx.x;
  if (t < n_band[r]) {
    const int l = band_lat[(r << 8) + t];
    const int pos = atomicAdd(&cursor[l], 1);
    entries[pos] = (r << 8) | t;
  }
}

__global__ __launch_bounds__(256) void sae_refine_lm(const float* __restrict__ xs,
                                                     const float* __restrict__ WT,
                                                     const float* __restrict__ lb,
                                                     const int* __restrict__ counts,
                                                     const int* __restrict__ offsets,
                                                     const int* __restrict__ entries,
                                                     double* __restrict__ band_eval) {
  __shared__ float4 wl[D_SZ / 4];
  const int l = blockIdx.x;
  const int t = threadIdx.x, lane = t & 63, w = t >> 6;
  const int n = counts[l];
  if (n == 0) return;
  const float4* wc = (const float4*)(WT + (size_t)l * D_SZ);
  for (int d = t; d < D_SZ / 4; d += 256) wl[d] = wc[d];
  __syncthreads();
  const int base = offsets[l];
  const double bias = (double)lb[l];
  for (int e = w; e < n; e += 4) {
    const int ent = entries[base + e];
    const int rr = ent >> 8;
    const float4* xr = (const float4*)(xs + (size_t)rr * D_SZ);
    double acc = 0.0;
#pragma unroll
    for (int i = 0; i < 5; ++i) {
      const float4 xv = xr[lane + 64 * i];
      const float4 wv = wl[lane + 64 * i];
      acc += (double)xv.x * (double)wv.x + (double)xv.y * (double)wv.y +
             (double)xv.z * (double)wv.z + (double)xv.w * (double)wv.w;
    }
#pragma unroll
    for (int off = 32; off > 0; off >>= 1) acc += __shfl_down(acc, off);
    if (lane == 0) band_eval[ent] = acc + bias;
  }
}

__global__ __launch_bounds__(320) void sae_finish_nz(const int* __restrict__ n_hi,
                                                     const int* __restrict__ n_band,
                                                     const int* __restrict__ band_lat,
                                                     const float* __restrict__ band_fval,
                                                     const double* __restrict__ band_eval,
                                                     int* __restrict__ t_idx,
                                                     float* __restrict__ t_val,
                                                     const unsigned short* __restrict__ Wdb,
                                                     const float* __restrict__ pb,
                                                     float* __restrict__ xhat) {
  __shared__ int bl[C_CAP];
  __shared__ float bf[C_CAP];
  __shared__ double be[C_CAP];
  __shared__ int ids[K_TOP];
  __shared__ float vs[K_TOP];
  const int r = blockIdx.x, t = threadIdx.x;
  const int nh = n_hi[r], nb = n_band[r];
  if (t < nb) {
    bl[t] = band_lat[(r << 8) + t];
    bf[t] = band_fval[(r << 8) + t];
    be[t] = band_eval[(r << 8) + t];
  }
  if (t < nh) {
    ids[t] = t_idx[(size_t)r * K_TOP + t];
    vs[t] = t_val[(size_t)r * K_TOP + t];
  }
  __syncthreads();
  const int need = K_TOP - nh;
  if (t < nb) {
    const double ev = be[t];
    const int l = bl[t];
    int rank = 0;
    for (int j = 0; j < nb; ++j) {
      const double e2 = be[j];
      if (e2 > ev || (e2 == ev && bl[j] < l)) ++rank;
    }
    if (rank < need) {
      const float fv = fmaxf(bf[t], 0.f);
      ids[nh + rank] = l;
      vs[nh + rank] = fv;
      t_idx[(size_t)r * K_TOP + nh + rank] = l;
      t_val[(size_t)r * K_TOP + nh + rank] = fv;
    }
  }
  __syncthreads();
  float4 acc = ((const float4*)pb)[t];
#pragma unroll 8
  for (int k = 0; k < K_TOP; ++k) {
    const ushort4 wv = ((const ushort4*)(Wdb + (size_t)ids[k] * D_SZ))[t];
    const float vk = vs[k];
    acc.x += vk * bf2f(wv.x);
    acc.y += vk * bf2f(wv.y);
    acc.z += vk * bf2f(wv.z);
    acc.w += vk * bf2f(wv.w);
  }
  ((float4*)(xhat + (size_t)r * D_SZ))[t] = acc;
}

__global__ void sae_scatterA(const int* __restrict__ top_idx, const float* __restrict__ top_val,
                             float* __restrict__ z) {
  const int r = blockIdx.x;
  const int t = threadIdx.x;
  const int id = top_idx[(size_t)r * K_TOP + t];
  const float v = top_val[(size_t)r * K_TOP + t];
  z[(size_t)r * L_SZ + id] = v;
}

__global__ __launch_bounds__(256) void sae_scatterB(const int* __restrict__ top_idx,
                                                    const float* __restrict__ top_val,
                                                    float* __restrict__ z) {
  __shared__ int ids[32 * K_TOP];
  __shared__ float vs[32 * K_TOP];
  const int t = threadIdx.x;
  for (int i = t; i < 32 * K_TOP; i += 256) {
    ids[i] = top_idx[(size_t)4064 * K_TOP + i];
    vs[i] = top_val[(size_t)4064 * K_TOP + i];
  }
  __syncthreads();
  float4* zz = (float4*)(z + (size_t)4064 * L_SZ);
  for (int i = t; i < 32 * L_SZ / 4; i += 256) zz[i] = make_float4(0.f, 0.f, 0.f, 0.f);
  __syncthreads();
  for (int i = t; i < 32 * K_TOP; i += 256) {
    const int rr = 4064 + i / K_TOP;
    z[(size_t)rr * L_SZ + ids[i]] = vs[i];
  }
}

extern "C" void kernel_launch(void* const* d_in, const int* in_sizes, int n_in,
                              void* d_out, int out_size, void* d_ws, size_t ws_size,
                              hipStream_t stream) {
  const float* x  = (const float*)d_in[0];
  const float* pb = (const float*)d_in[1];
  const float* We = (const float*)d_in[2];
  const float* lb = (const float*)d_in[3];
  const float* Wd = (const float*)d_in[4];

  float* zpre = (float*)d_out;
  float* z    = zpre + (size_t)B_SZ * L_SZ;
  float* xhat = z + (size_t)B_SZ * L_SZ;

  const bool use_ws = ws_size >= ((size_t)251 << 20);
  char* sb = use_ws ? (char*)d_ws : (char*)z;

  unsigned short* A_bf   = (unsigned short*)(sb);                        // 10 MiB
  unsigned short* WT_bf  = (unsigned short*)(sb + ((size_t)16 << 20));   // 40 MiB
  float*          WT_f32 = (float*)(sb + ((size_t)64 << 20));            // 80 MiB
  float*          xs_f32 = (float*)(sb + ((size_t)144 << 20));           // 20 MiB
  int*            b_lat  = (int*)(sb + ((size_t)164 << 20));             // 4 MiB
  float*          b_fval = (float*)(sb + ((size_t)168 << 20));           // 4 MiB
  double*         b_eval = (double*)(sb + ((size_t)172 << 20));          // 8 MiB
  int*            bk_cnt = (int*)(sb + ((size_t)180 << 20));             // 64 KiB
  int*            bk_off = (int*)(sb + ((size_t)181 << 20));             // 64 KiB
  int*            bk_cur = (int*)(sb + ((size_t)182 << 20));             // 64 KiB
  int*            bk_ent = (int*)(sb + ((size_t)184 << 20));             // 3 MiB
  unsigned short* Wd_bf  = (unsigned short*)(sb + ((size_t)188 << 20));  // 40 MiB
  int*            nhi_g  = (int*)(sb + ((size_t)228 << 20));             // 16 KiB
  int*            nbd_g  = (int*)(sb + ((size_t)229 << 20));             // 16 KiB
  int*            cl_idx = (int*)(sb + ((size_t)234 << 20));             // 8 MiB
  float*          cl_val = (float*)(sb + ((size_t)242 << 20));           // 8 MiB
  int*            cl_cnt = (int*)(sb + ((size_t)250 << 20));             // 16 KiB
  int*   t_idx = use_ws ? (int*)(sb + ((size_t)230 << 20))
                        : (int*)((char*)z + ((size_t)254 << 20));        // 1 MiB
  float* t_val = use_ws ? (float*)(sb + ((size_t)232 << 20))
                        : (float*)((char*)z + ((size_t)255 << 20));      // 1 MiB

  sae_prep<<<11344, 256, 0, stream>>>(x, pb, We, Wd, A_bf, xs_f32, WT_f32, WT_bf, Wd_bf,
                                      bk_cnt, cl_cnt);
  sae_gemm<<<1024, 512, 0, stream>>>(A_bf, WT_bf, lb, zpre, cl_cnt, cl_idx, cl_val);
  if (use_ws) {
    sae_mega<<<B_SZ, 512, 0, stream>>>(zpre, xs_f32, WT_f32, lb, Wd_bf, pb,
                                       cl_cnt, cl_idx, cl_val, z, xhat);
  } else {
    sae_topc<<<B_SZ, 256, 0, stream>>>(zpre, bk_cnt, b_lat, b_fval, nhi_g, nbd_g, t_idx, t_val);
    sae_scan<<<1, 256, 0, stream>>>(bk_cnt, bk_off, bk_cur);
    sae_bucket_fill<<<B_SZ, 192, 0, stream>>>(b_lat, nbd_g, bk_cur, bk_ent);
    sae_refine_lm<<<L_SZ, 256, 0, stream>>>(xs_f32, WT_f32, lb, bk_cnt, bk_off, bk_ent, b_eval);
    sae_finish_nz<<<B_SZ, 320, 0, stream>>>(nhi_g, nbd_g, b_lat, b_fval, b_eval, t_idx, t_val,
                                            Wd_bf, pb, xhat);
    hipMemsetAsync(z, 0, (size_t)4064 * L_SZ * sizeof(float), stream);
    sae_scatterA<<<4064, K_TOP, 0, stream>>>(t_idx, t_val, z);
    sae_scatterB<<<1, 256, 0, stream>>>(t_idx, t_val, z);
  }
}